// Round 1
// baseline (982.253 us; speedup 1.0000x reference)
//
#include <hip/hip_runtime.h>
#include <math.h>

// ContinuousFilterConv: fused edge-MLP + gather + attention + atomic scatter.
// fp32 throughout (no fp32 MFMA on CDNA4 -> vector ALU; bf16-MFMA is the
// planned round-2 upgrade if profiling shows VALU-bound).
//
// Block = 256 threads handles TE=64 edges.
// Thread t: f0=(t&15)*4 features, e0=(t>>4)*4 edges -> 4x4 register tile.
// LDS: W1s/W2s (stride 64, b128 reads are 2-way aliased = free),
//      Es edge tile transposed (stride 65: writes 2-way, reads broadcast).

#define TE 64          // edges per block
#define HID 64
#define ESTRIDE 65     // padded LDS stride for transposed tiles

__global__ __launch_bounds__(256) void edge_mlp_scatter(
    const float* __restrict__ atom,       // [N,64]
    const float* __restrict__ edge_emb,   // [E,64]
    const float* __restrict__ W1,         // [64,64]
    const float* __restrict__ b1,         // [64]
    const float* __restrict__ W2,         // [64,64]
    const float* __restrict__ b2,         // [64]
    const float* __restrict__ coef,       // [64]
    const int*   __restrict__ edge_list,  // [E,2] int32: [dest, src]
    float* __restrict__ num,              // [N,64] pre-zeroed (d_out)
    float* __restrict__ den,              // [N]    pre-zeroed (ws)
    int E)
{
    __shared__ float W1s[HID * HID];
    __shared__ float W2s[HID * HID];
    __shared__ float Es[HID * ESTRIDE];   // GEMM1: Et[k][e]; then reused as Ht[k2][e]
    __shared__ float b1s[HID], b2s[HID], cfs[HID];
    __shared__ int   dsts[TE], srcs[TE];

    const int t  = threadIdx.x;
    const int eb = blockIdx.x * TE;

    // ---- stage weights / biases / edge list ----
    #pragma unroll
    for (int i = 0; i < 16; ++i) {
        W1s[t + 256 * i] = W1[t + 256 * i];
        W2s[t + 256 * i] = W2[t + 256 * i];
    }
    if (t < HID) { b1s[t] = b1[t]; b2s[t] = b2[t]; cfs[t] = coef[t]; }
    if (t >= 64 && t < 64 + TE) {
        int e  = t - 64;
        int eg = eb + e;
        if (eg >= E) eg = E - 1;           // clamp (E % 64 == 0 in practice)
        dsts[e] = edge_list[eg * 2 + 0];
        srcs[e] = edge_list[eg * 2 + 1];
    }

    // ---- stage edge tile transposed: Es[k][e], thread t: e=t/4, k0=(t%4)*16 ----
    {
        const int e  = t >> 2;
        const int k0 = (t & 3) * 16;
        int eg = eb + e;
        if (eg >= E) eg = E - 1;
        const float* sp = edge_emb + (size_t)eg * HID + k0;
        float4 a0 = ((const float4*)sp)[0];
        float4 a1 = ((const float4*)sp)[1];
        float4 a2 = ((const float4*)sp)[2];
        float4 a3 = ((const float4*)sp)[3];
        float vv[16] = {a0.x,a0.y,a0.z,a0.w, a1.x,a1.y,a1.z,a1.w,
                        a2.x,a2.y,a2.z,a2.w, a3.x,a3.y,a3.z,a3.w};
        #pragma unroll
        for (int j = 0; j < 16; ++j)
            Es[(k0 + j) * ESTRIDE + e] = vv[j];   // banks: (k0+j+e)%32 -> 2-way, free
    }
    __syncthreads();

    const int f0 = (t & 15) * 4;
    const int g  = t >> 4;          // edge-group id, e0 = 4g
    const int e0 = g * 4;

    // ---- GEMM1: h1[e][f] = sum_k Es[k][e] * W1s[k][f] ----
    float acc[4][4] = {{0.f,0.f,0.f,0.f},{0.f,0.f,0.f,0.f},
                       {0.f,0.f,0.f,0.f},{0.f,0.f,0.f,0.f}};
    #pragma unroll 8
    for (int k = 0; k < HID; ++k) {
        float4 w = *(const float4*)&W1s[k * HID + f0];
        float ev[4];
        #pragma unroll
        for (int c = 0; c < 4; ++c) ev[c] = Es[k * ESTRIDE + e0 + c];
        #pragma unroll
        for (int ce = 0; ce < 4; ++ce) {
            acc[ce][0] = fmaf(ev[ce], w.x, acc[ce][0]);
            acc[ce][1] = fmaf(ev[ce], w.y, acc[ce][1]);
            acc[ce][2] = fmaf(ev[ce], w.z, acc[ce][2]);
            acc[ce][3] = fmaf(ev[ce], w.w, acc[ce][3]);
        }
    }

    // ---- bias + tanh, write transposed Ht[k2=f][e] back into Es ----
    float h[4][4];
    #pragma unroll
    for (int ce = 0; ce < 4; ++ce)
        #pragma unroll
        for (int cf = 0; cf < 4; ++cf)
            h[ce][cf] = tanhf(acc[ce][cf] + b1s[f0 + cf]);

    __syncthreads();  // all Es reads done before overwrite
    #pragma unroll
    for (int cf = 0; cf < 4; ++cf) {
        #pragma unroll
        for (int j = 0; j < 4; ++j) {
            int ce = (j + g) & 3;   // rotation spreads banks: 2-way, free
            Es[(f0 + cf) * ESTRIDE + e0 + ce] = h[ce][cf];
        }
    }
    __syncthreads();

    // ---- GEMM2: h2[e][f] = b2[f] + sum_k Ht[k][e] * W2s[k][f] ----
    float acc2[4][4] = {{0.f,0.f,0.f,0.f},{0.f,0.f,0.f,0.f},
                        {0.f,0.f,0.f,0.f},{0.f,0.f,0.f,0.f}};
    #pragma unroll 8
    for (int k = 0; k < HID; ++k) {
        float4 w = *(const float4*)&W2s[k * HID + f0];
        float ev[4];
        #pragma unroll
        for (int c = 0; c < 4; ++c) ev[c] = Es[k * ESTRIDE + e0 + c];
        #pragma unroll
        for (int ce = 0; ce < 4; ++ce) {
            acc2[ce][0] = fmaf(ev[ce], w.x, acc2[ce][0]);
            acc2[ce][1] = fmaf(ev[ce], w.y, acc2[ce][1]);
            acc2[ce][2] = fmaf(ev[ce], w.z, acc2[ce][2]);
            acc2[ce][3] = fmaf(ev[ce], w.w, acc2[ce][3]);
        }
    }

    // ---- gather atom[src], msg, attention dot, scatter ----
    float4 cf4 = *(const float4*)&cfs[f0];
    float msg[4][4];
    float partial[4];
    #pragma unroll
    for (int ce = 0; ce < 4; ++ce) {
        int s = srcs[e0 + ce];
        float4 a = *(const float4*)&atom[(size_t)s * HID + f0];
        float h2x = acc2[ce][0] + b2s[f0 + 0];
        float h2y = acc2[ce][1] + b2s[f0 + 1];
        float h2z = acc2[ce][2] + b2s[f0 + 2];
        float h2w = acc2[ce][3] + b2s[f0 + 3];
        msg[ce][0] = a.x * h2x;
        msg[ce][1] = a.y * h2y;
        msg[ce][2] = a.z * h2z;
        msg[ce][3] = a.w * h2w;
        partial[ce] = msg[ce][0]*cf4.x + msg[ce][1]*cf4.y
                    + msg[ce][2]*cf4.z + msg[ce][3]*cf4.w;
    }
    // butterfly over the 16 lanes sharing this edge group (xor of bits 0..3)
    #pragma unroll
    for (int m = 1; m < 16; m <<= 1) {
        #pragma unroll
        for (int ce = 0; ce < 4; ++ce)
            partial[ce] += __shfl_xor(partial[ce], m);
    }

    #pragma unroll
    for (int ce = 0; ce < 4; ++ce) {
        if (eb + e0 + ce >= E) continue;
        float at = expf(partial[ce]);
        int d = dsts[e0 + ce];
        float* np = num + (size_t)d * HID + f0;
        atomicAdd(np + 0, msg[ce][0] * at);
        atomicAdd(np + 1, msg[ce][1] * at);
        atomicAdd(np + 2, msg[ce][2] * at);
        atomicAdd(np + 3, msg[ce][3] * at);
        if ((t & 15) == 0) atomicAdd(&den[d], at);
    }
}

// out[n][f] = den[n] > 0 ? num[n][f]/den[n] : num[n][f]   (in place on d_out)
__global__ __launch_bounds__(256) void finalize_kernel(
    float* __restrict__ out, const float* __restrict__ den, int n16)
{
    int i = blockIdx.x * blockDim.x + threadIdx.x;
    if (i >= n16) return;
    float d = den[i >> 4];
    if (d > 0.f) {
        float4* p = (float4*)out + i;
        float4 v = *p;
        float r = 1.0f / d;
        v.x *= r; v.y *= r; v.z *= r; v.w *= r;
        *p = v;
    }
}

extern "C" void kernel_launch(void* const* d_in, const int* in_sizes, int n_in,
                              void* d_out, int out_size, void* d_ws, size_t ws_size,
                              hipStream_t stream) {
    const float* atom      = (const float*)d_in[0];
    const float* edge_emb  = (const float*)d_in[1];
    const float* W1        = (const float*)d_in[2];
    const float* b1        = (const float*)d_in[3];
    const float* W2        = (const float*)d_in[4];
    const float* b2        = (const float*)d_in[5];
    const float* coef      = (const float*)d_in[6];
    const int*   edge_list = (const int*)d_in[7];   // int32 (JAX x64 disabled)

    const int N = in_sizes[0] / HID;   // 50000
    const int E = in_sizes[1] / HID;   // 800000

    float* num = (float*)d_out;        // accumulate numerator directly in d_out
    float* den = (float*)d_ws;         // N floats of workspace

    hipMemsetAsync(d_out, 0, (size_t)N * HID * sizeof(float), stream);
    hipMemsetAsync(d_ws, 0, (size_t)N * sizeof(float), stream);

    int nblk = (E + TE - 1) / TE;      // 12500
    edge_mlp_scatter<<<nblk, 256, 0, stream>>>(
        atom, edge_emb, W1, b1, W2, b2, coef, edge_list, num, den, E);

    int n16 = N * (HID / 4);           // float4 elements
    finalize_kernel<<<(n16 + 255) / 256, 256, 0, stream>>>(num, den, n16);
}

// Round 2
// 732.499 us; speedup vs baseline: 1.3410x; 1.3410x over previous
//
#include <hip/hip_runtime.h>
#include <math.h>

// ContinuousFilterConv, round 2: dest-sorted edge processing.
// R1 post-mortem: atomic scatter wrote 825 MB to HBM (vs 13 MB ideal) and
// serialized on avg-degree-16 contention -> 766 us with VALUBusy only 27%.
// Fix: counting-sort edges by dest (hist + scan + position scatter into ws),
// then the fused MLP kernel processes sorted tiles and segment-reduces in LDS
// before one atomicAdd per (distinct dest, feature) -> ~4M atomics vs 52M.

#define TE 64          // edges per block
#define HID 64
#define ESTRIDE 65     // padded LDS stride

// ---------------- sort pipeline ----------------

__global__ __launch_bounds__(256) void hist_kernel(
    const int* __restrict__ edge_list, int* __restrict__ cursor, int E)
{
    int i = blockIdx.x * blockDim.x + threadIdx.x;
    if (i < E) atomicAdd(&cursor[edge_list[2 * i]], 1);
}

// single-block exclusive scan over N ints, in place (N up to ~1M fine)
__global__ __launch_bounds__(1024) void scan_kernel(int* __restrict__ a, int N)
{
    __shared__ int wsum[16];
    __shared__ int carry_s;
    const int t = threadIdx.x;
    const int lane = t & 63, wv = t >> 6;
    if (t == 0) carry_s = 0;
    __syncthreads();
    for (int base = 0; base < N; base += 1024) {
        int i = base + t;
        int x = (i < N) ? a[i] : 0;
        int v = x;
        #pragma unroll
        for (int d = 1; d < 64; d <<= 1) {
            int y = __shfl_up(v, d);
            if (lane >= d) v += y;
        }
        if (lane == 63) wsum[wv] = v;
        __syncthreads();
        if (wv == 0 && lane < 16) {
            int s = wsum[lane];
            #pragma unroll
            for (int d = 1; d < 16; d <<= 1) {
                int y = __shfl_up(s, d);
                if (lane >= d) s += y;
            }
            wsum[lane] = s;
        }
        __syncthreads();
        int waveoff = (wv == 0) ? 0 : wsum[wv - 1];
        int incl = v + waveoff + carry_s;
        if (i < N) a[i] = incl - x;        // exclusive
        __syncthreads();
        if (t == 1023) carry_s = incl;
        __syncthreads();
    }
}

__global__ __launch_bounds__(256) void perm_kernel(
    const int* __restrict__ edge_list, int* __restrict__ cursor,
    int* __restrict__ perm, int E)
{
    int i = blockIdx.x * blockDim.x + threadIdx.x;
    if (i < E) {
        int d = edge_list[2 * i];
        int p = atomicAdd(&cursor[d], 1);
        perm[p] = i;
    }
}

// ---------------- fused MLP + segment-reduced scatter ----------------

__global__ __launch_bounds__(256) void edge_mlp_sorted(
    const float* __restrict__ atom,       // [N,64]
    const float* __restrict__ edge_emb,   // [E,64]
    const float* __restrict__ W1,         // [64,64]
    const float* __restrict__ b1,         // [64]
    const float* __restrict__ W2,         // [64,64]
    const float* __restrict__ b2,         // [64]
    const float* __restrict__ coef,       // [64]
    const int*   __restrict__ edge_list,  // [E,2] int32: [dest, src]
    const int*   __restrict__ perm,       // [E] edge ids sorted by dest
    float* __restrict__ num,              // [N,64] pre-zeroed (d_out)
    float* __restrict__ den,              // [N]    pre-zeroed (ws)
    int E)
{
    __shared__ float W1s[HID * HID];
    __shared__ float W2s[HID * HID];
    __shared__ float Es[HID * ESTRIDE];   // edge tile -> Ht -> segment accumulator
    __shared__ float b1s[HID], b2s[HID], cfs[HID];
    __shared__ float denacc[TE];
    __shared__ int   dsts[TE], srcs[TE], pidx[TE], seg[TE], segdest[TE];
    __shared__ int   nseg_s;

    const int t  = threadIdx.x;
    const int eb = blockIdx.x * TE;

    // ---- phase 0: weights + permutation tile ----
    #pragma unroll
    for (int i = 0; i < 16; ++i) {
        W1s[t + 256 * i] = W1[t + 256 * i];
        W2s[t + 256 * i] = W2[t + 256 * i];
    }
    if (t < HID) { b1s[t] = b1[t]; b2s[t] = b2[t]; cfs[t] = coef[t]; }
    if (t < TE) {
        int eg = eb + t;
        if (eg >= E) eg = E - 1;
        pidx[t] = perm[eg];
    }
    __syncthreads();

    // ---- phase 1: edge rows (transposed) + dest/src + segment ids ----
    if (t < TE) {                          // wave 0: contiguous lanes 0..63
        int e = pidx[t];
        int d = edge_list[2 * e + 0];
        int s = edge_list[2 * e + 1];
        dsts[t] = d; srcs[t] = s;
        int dprev = __shfl_up(d, 1);
        int head = (t == 0 || dprev != d) ? 1 : 0;
        int sv = head;
        #pragma unroll
        for (int m = 1; m < 64; m <<= 1) {
            int y = __shfl_up(sv, m);
            if (t >= m) sv += y;
        }
        int sidx = sv - 1;
        seg[t] = sidx;
        if (head) segdest[sidx] = d;
        if (t == 63) nseg_s = sv;
    }
    {
        const int e  = t >> 2;
        const int k0 = (t & 3) * 16;
        const float* sp = edge_emb + (size_t)pidx[e] * HID + k0;
        float4 a0 = ((const float4*)sp)[0];
        float4 a1 = ((const float4*)sp)[1];
        float4 a2 = ((const float4*)sp)[2];
        float4 a3 = ((const float4*)sp)[3];
        float vv[16] = {a0.x,a0.y,a0.z,a0.w, a1.x,a1.y,a1.z,a1.w,
                        a2.x,a2.y,a2.z,a2.w, a3.x,a3.y,a3.z,a3.w};
        #pragma unroll
        for (int j = 0; j < 16; ++j)
            Es[(k0 + j) * ESTRIDE + e] = vv[j];
    }
    __syncthreads();

    const int f0 = (t & 15) * 4;
    const int g  = t >> 4;
    const int e0 = g * 4;

    // ---- GEMM1 ----
    float acc[4][4] = {{0.f,0.f,0.f,0.f},{0.f,0.f,0.f,0.f},
                       {0.f,0.f,0.f,0.f},{0.f,0.f,0.f,0.f}};
    #pragma unroll 8
    for (int k = 0; k < HID; ++k) {
        float4 w = *(const float4*)&W1s[k * HID + f0];
        float ev[4];
        #pragma unroll
        for (int c = 0; c < 4; ++c) ev[c] = Es[k * ESTRIDE + e0 + c];
        #pragma unroll
        for (int ce = 0; ce < 4; ++ce) {
            acc[ce][0] = fmaf(ev[ce], w.x, acc[ce][0]);
            acc[ce][1] = fmaf(ev[ce], w.y, acc[ce][1]);
            acc[ce][2] = fmaf(ev[ce], w.z, acc[ce][2]);
            acc[ce][3] = fmaf(ev[ce], w.w, acc[ce][3]);
        }
    }

    // ---- bias + tanh, transposed writeback ----
    float h[4][4];
    #pragma unroll
    for (int ce = 0; ce < 4; ++ce)
        #pragma unroll
        for (int cf = 0; cf < 4; ++cf)
            h[ce][cf] = tanhf(acc[ce][cf] + b1s[f0 + cf]);

    __syncthreads();
    #pragma unroll
    for (int cf = 0; cf < 4; ++cf) {
        #pragma unroll
        for (int j = 0; j < 4; ++j) {
            int ce = (j + g) & 3;
            Es[(f0 + cf) * ESTRIDE + e0 + ce] = h[ce][cf];
        }
    }
    __syncthreads();

    // ---- GEMM2 ----
    float acc2[4][4] = {{0.f,0.f,0.f,0.f},{0.f,0.f,0.f,0.f},
                        {0.f,0.f,0.f,0.f},{0.f,0.f,0.f,0.f}};
    #pragma unroll 8
    for (int k = 0; k < HID; ++k) {
        float4 w = *(const float4*)&W2s[k * HID + f0];
        float ev[4];
        #pragma unroll
        for (int c = 0; c < 4; ++c) ev[c] = Es[k * ESTRIDE + e0 + c];
        #pragma unroll
        for (int ce = 0; ce < 4; ++ce) {
            acc2[ce][0] = fmaf(ev[ce], w.x, acc2[ce][0]);
            acc2[ce][1] = fmaf(ev[ce], w.y, acc2[ce][1]);
            acc2[ce][2] = fmaf(ev[ce], w.z, acc2[ce][2]);
            acc2[ce][3] = fmaf(ev[ce], w.w, acc2[ce][3]);
        }
    }
    __syncthreads();                      // Es reads done; safe to repurpose

    // ---- zero segment accumulator (reuse Es) + denacc ----
    for (int i = t; i < HID * ESTRIDE; i += 256) Es[i] = 0.f;
    if (t < TE) denacc[t] = 0.f;

    // ---- gather atom[src], msg, attention (registers/global only) ----
    float4 cf4 = *(const float4*)&cfs[f0];
    float msg[4][4];
    float partial[4];
    #pragma unroll
    for (int ce = 0; ce < 4; ++ce) {
        int s = srcs[e0 + ce];
        float4 a = *(const float4*)&atom[(size_t)s * HID + f0];
        float h2x = acc2[ce][0] + b2s[f0 + 0];
        float h2y = acc2[ce][1] + b2s[f0 + 1];
        float h2z = acc2[ce][2] + b2s[f0 + 2];
        float h2w = acc2[ce][3] + b2s[f0 + 3];
        msg[ce][0] = a.x * h2x;
        msg[ce][1] = a.y * h2y;
        msg[ce][2] = a.z * h2z;
        msg[ce][3] = a.w * h2w;
        partial[ce] = msg[ce][0]*cf4.x + msg[ce][1]*cf4.y
                    + msg[ce][2]*cf4.z + msg[ce][3]*cf4.w;
    }
    #pragma unroll
    for (int m = 1; m < 16; m <<= 1) {
        #pragma unroll
        for (int ce = 0; ce < 4; ++ce)
            partial[ce] += __shfl_xor(partial[ce], m);
    }
    float at[4];
    #pragma unroll
    for (int ce = 0; ce < 4; ++ce)
        at[ce] = (eb + e0 + ce < E) ? expf(partial[ce]) : 0.f;

    __syncthreads();                      // zeroing complete before accumulation

    // ---- register run-combine over this group's 4 sorted edges, then
    //      LDS-atomic into segment accumulator ----
    {
        int curseg = seg[e0];
        float r0 = msg[0][0]*at[0], r1 = msg[0][1]*at[0];
        float r2 = msg[0][2]*at[0], r3 = msg[0][3]*at[0];
        float rd = at[0];
        #pragma unroll
        for (int ce = 1; ce < 4; ++ce) {
            int s2 = seg[e0 + ce];
            if (s2 == curseg) {
                r0 = fmaf(msg[ce][0], at[ce], r0);
                r1 = fmaf(msg[ce][1], at[ce], r1);
                r2 = fmaf(msg[ce][2], at[ce], r2);
                r3 = fmaf(msg[ce][3], at[ce], r3);
                rd += at[ce];
            } else {
                float* p = &Es[curseg * ESTRIDE + f0];
                atomicAdd(p + 0, r0); atomicAdd(p + 1, r1);
                atomicAdd(p + 2, r2); atomicAdd(p + 3, r3);
                if ((t & 15) == 0) atomicAdd(&denacc[curseg], rd);
                curseg = s2;
                r0 = msg[ce][0]*at[ce]; r1 = msg[ce][1]*at[ce];
                r2 = msg[ce][2]*at[ce]; r3 = msg[ce][3]*at[ce];
                rd = at[ce];
            }
        }
        float* p = &Es[curseg * ESTRIDE + f0];
        atomicAdd(p + 0, r0); atomicAdd(p + 1, r1);
        atomicAdd(p + 2, r2); atomicAdd(p + 3, r3);
        if ((t & 15) == 0) atomicAdd(&denacc[curseg], rd);
    }
    __syncthreads();

    // ---- flush: one atomicAdd per (segment, feature) ----
    {
        int nseg = nseg_s;
        int s = t >> 2;
        int q = t & 3;
        if (s < nseg) {
            int d = segdest[s];
            float* np = num + (size_t)d * HID + q * 16;
            const float* sp = &Es[s * ESTRIDE + q * 16];
            #pragma unroll
            for (int j = 0; j < 16; ++j) atomicAdd(np + j, sp[j]);
            if (q == 0) atomicAdd(&den[d], denacc[s]);
        }
    }
}

__global__ __launch_bounds__(256) void finalize_kernel(
    float* __restrict__ out, const float* __restrict__ den, int n16)
{
    int i = blockIdx.x * blockDim.x + threadIdx.x;
    if (i >= n16) return;
    float d = den[i >> 4];
    if (d > 0.f) {
        float4* p = (float4*)out + i;
        float4 v = *p;
        float r = 1.0f / d;
        v.x *= r; v.y *= r; v.z *= r; v.w *= r;
        *p = v;
    }
}

extern "C" void kernel_launch(void* const* d_in, const int* in_sizes, int n_in,
                              void* d_out, int out_size, void* d_ws, size_t ws_size,
                              hipStream_t stream) {
    const float* atom      = (const float*)d_in[0];
    const float* edge_emb  = (const float*)d_in[1];
    const float* W1        = (const float*)d_in[2];
    const float* b1        = (const float*)d_in[3];
    const float* W2        = (const float*)d_in[4];
    const float* b2        = (const float*)d_in[5];
    const float* coef      = (const float*)d_in[6];
    const int*   edge_list = (const int*)d_in[7];   // int32

    const int N = in_sizes[0] / HID;   // 50000
    const int E = in_sizes[1] / HID;   // 800000

    // ws layout: [den: N floats][cursor: N ints][perm: E ints]
    float* den    = (float*)d_ws;
    int*   cursor = (int*)d_ws + N;
    int*   perm   = (int*)d_ws + 2 * N;

    hipMemsetAsync(d_out, 0, (size_t)N * HID * sizeof(float), stream);
    hipMemsetAsync(d_ws, 0, (size_t)(2 * N) * sizeof(int), stream);  // den+cursor

    int eblk = (E + 255) / 256;
    hist_kernel<<<eblk, 256, 0, stream>>>(edge_list, cursor, E);
    scan_kernel<<<1, 1024, 0, stream>>>(cursor, N);
    perm_kernel<<<eblk, 256, 0, stream>>>(edge_list, cursor, perm, E);

    int nblk = (E + TE - 1) / TE;      // 12500
    edge_mlp_sorted<<<nblk, 256, 0, stream>>>(
        atom, edge_emb, W1, b1, W2, b2, coef, edge_list, perm,
        (float*)d_out, den, E);

    int n16 = N * (HID / 4);
    finalize_kernel<<<(n16 + 255) / 256, 256, 0, stream>>>((float*)d_out, den, n16);
}

// Round 3
// 622.939 us; speedup vs baseline: 1.5768x; 1.1759x over previous
//
#include <hip/hip_runtime.h>
#include <math.h>

// ContinuousFilterConv, round 3.
// R2 post-mortem: main kernel 400 us (VALUBusy 57%), but ~315 us hidden in
// the sort pipeline -- the single-block scan over 50000 counters serializes
// on one CU. This round: (1) hierarchical 3-kernel scan, (2) main-kernel
// occupancy 3->4 blocks/CU by staging W2 through registers into W1s's LDS
// after GEMM1 (saves 16 KB), fast tanh via v_exp+v_rcp, (3) flush uses plain
// coalesced stores for tile-interior dests (only boundary segments need
// atomics when edges are dest-sorted).

#define TE 64          // edges per block
#define HID 64
#define ESTRIDE 65     // padded LDS stride

__device__ __forceinline__ float fast_tanh(float x) {
    // tanh(x) = 1 - 2/(exp(2x)+1); saturates to +-1 correctly (rcp(inf)=0)
    float t = __expf(2.0f * x);
    return 1.0f - 2.0f * __builtin_amdgcn_rcpf(t + 1.0f);
}

// ---------------- sort pipeline ----------------

__global__ __launch_bounds__(256) void hist_kernel(
    const int2* __restrict__ edge_list, int* __restrict__ cursor, int E)
{
    int i = blockIdx.x * blockDim.x + threadIdx.x;
    if (i < E) atomicAdd(&cursor[edge_list[i].x], 1);
}

// per-block exclusive scan of 1024 elements; block total -> blocksums
__global__ __launch_bounds__(1024) void scanA_kernel(
    int* __restrict__ a, int* __restrict__ blocksums, int N)
{
    __shared__ int wsum[16];
    const int t = threadIdx.x;
    const int lane = t & 63, wv = t >> 6;
    int i = blockIdx.x * 1024 + t;
    int x = (i < N) ? a[i] : 0;
    int v = x;
    #pragma unroll
    for (int d = 1; d < 64; d <<= 1) {
        int y = __shfl_up(v, d);
        if (lane >= d) v += y;
    }
    if (lane == 63) wsum[wv] = v;
    __syncthreads();
    if (wv == 0 && lane < 16) {
        int s = wsum[lane];
        #pragma unroll
        for (int d = 1; d < 16; d <<= 1) {
            int y = __shfl_up(s, d);
            if (lane >= d) s += y;
        }
        wsum[lane] = s;
    }
    __syncthreads();
    int incl = v + ((wv == 0) ? 0 : wsum[wv - 1]);
    if (i < N) a[i] = incl - x;                 // block-local exclusive
    if (t == 1023) blocksums[blockIdx.x] = incl;
}

// single-wave exclusive scan of nb (<=64) block sums
__global__ __launch_bounds__(64) void scanB_kernel(int* __restrict__ bs, int nb)
{
    int lane = threadIdx.x;
    int x = (lane < nb) ? bs[lane] : 0;
    int v = x;
    #pragma unroll
    for (int d = 1; d < 64; d <<= 1) {
        int y = __shfl_up(v, d);
        if (lane >= d) v += y;
    }
    if (lane < nb) bs[lane] = v - x;
}

__global__ __launch_bounds__(1024) void scanC_kernel(
    int* __restrict__ a, const int* __restrict__ blocksums, int N)
{
    int i = blockIdx.x * 1024 + threadIdx.x;
    if (i < N) a[i] += blocksums[blockIdx.x];
}

__global__ __launch_bounds__(256) void perm_kernel(
    const int2* __restrict__ edge_list, int* __restrict__ cursor,
    int* __restrict__ perm, int E)
{
    int i = blockIdx.x * blockDim.x + threadIdx.x;
    if (i < E) {
        int d = edge_list[i].x;
        int p = atomicAdd(&cursor[d], 1);
        perm[p] = i;
    }
}

// ---------------- fused MLP + segment-reduced scatter ----------------

__global__ __launch_bounds__(256, 4) void edge_mlp_sorted(
    const float* __restrict__ atom,       // [N,64]
    const float* __restrict__ edge_emb,   // [E,64]
    const float* __restrict__ W1,         // [64,64]
    const float* __restrict__ b1,         // [64]
    const float* __restrict__ W2,         // [64,64]
    const float* __restrict__ b2,         // [64]
    const float* __restrict__ coef,       // [64]
    const int*   __restrict__ edge_list,  // [E,2] int32: [dest, src]
    const int*   __restrict__ perm,       // [E] edge ids sorted by dest
    float* __restrict__ num,              // [N,64] pre-zeroed (d_out)
    float* __restrict__ den,              // [N]    pre-zeroed (ws)
    int E)
{
    __shared__ float W1s[HID * HID];      // W1 for GEMM1; W2 for GEMM2
    __shared__ float Es[HID * ESTRIDE];   // edge tile -> Ht -> segment accum
    __shared__ float b1s[HID], b2s[HID], cfs[HID];
    __shared__ float denacc[TE];
    __shared__ int   srcs[TE], pidx[TE], seg[TE], segdest[TE];
    __shared__ int   nseg_s, prevd_s, nextd_s;

    const int t  = threadIdx.x;
    const int eb = blockIdx.x * TE;

    // ---- phase 0: W1 -> LDS, W2 -> regs, biases, perm tile ----
    float w2r[16];
    #pragma unroll
    for (int i = 0; i < 16; ++i) {
        W1s[t + 256 * i] = W1[t + 256 * i];
        w2r[i] = W2[t + 256 * i];
    }
    if (t < HID) { b1s[t] = b1[t]; b2s[t] = b2[t]; cfs[t] = coef[t]; }
    if (t < TE) {
        int eg = eb + t;
        if (eg >= E) eg = E - 1;
        pidx[t] = perm[eg];
    }
    __syncthreads();

    // ---- phase 1: seg ids (wave 0), boundary dests (thread 64), edge tile ----
    if (t < TE) {                          // wave 0: contiguous lanes 0..63
        int e = pidx[t];
        int d = edge_list[2 * e + 0];
        int s = edge_list[2 * e + 1];
        srcs[t] = s;
        int dprev = __shfl_up(d, 1);
        int head = (t == 0 || dprev != d) ? 1 : 0;
        int sv = head;
        #pragma unroll
        for (int m = 1; m < 64; m <<= 1) {
            int y = __shfl_up(sv, m);
            if (t >= m) sv += y;
        }
        int sidx = sv - 1;
        seg[t] = sidx;
        if (head) segdest[sidx] = d;
        if (t == 63) nseg_s = sv;
    } else if (t == 64) {
        int pd = -1, nd = -1;
        if (eb > 0)          pd = edge_list[2 * perm[eb - 1]];
        if (eb + TE < E)     nd = edge_list[2 * perm[eb + TE]];
        prevd_s = pd; nextd_s = nd;
    }
    {
        const int e  = t >> 2;
        const int k0 = (t & 3) * 16;
        const float* sp = edge_emb + (size_t)pidx[e] * HID + k0;
        float4 a0 = ((const float4*)sp)[0];
        float4 a1 = ((const float4*)sp)[1];
        float4 a2 = ((const float4*)sp)[2];
        float4 a3 = ((const float4*)sp)[3];
        float vv[16] = {a0.x,a0.y,a0.z,a0.w, a1.x,a1.y,a1.z,a1.w,
                        a2.x,a2.y,a2.z,a2.w, a3.x,a3.y,a3.z,a3.w};
        #pragma unroll
        for (int j = 0; j < 16; ++j)
            Es[(k0 + j) * ESTRIDE + e] = vv[j];
    }
    __syncthreads();

    const int f0 = (t & 15) * 4;
    const int g  = t >> 4;
    const int e0 = g * 4;

    // ---- GEMM1: h1[e][f] = sum_k Es[k][e] * W1s[k][f] ----
    float acc[4][4] = {{0.f,0.f,0.f,0.f},{0.f,0.f,0.f,0.f},
                       {0.f,0.f,0.f,0.f},{0.f,0.f,0.f,0.f}};
    #pragma unroll 8
    for (int k = 0; k < HID; ++k) {
        float4 w = *(const float4*)&W1s[k * HID + f0];
        float ev[4];
        #pragma unroll
        for (int c = 0; c < 4; ++c) ev[c] = Es[k * ESTRIDE + e0 + c];
        #pragma unroll
        for (int ce = 0; ce < 4; ++ce) {
            acc[ce][0] = fmaf(ev[ce], w.x, acc[ce][0]);
            acc[ce][1] = fmaf(ev[ce], w.y, acc[ce][1]);
            acc[ce][2] = fmaf(ev[ce], w.z, acc[ce][2]);
            acc[ce][3] = fmaf(ev[ce], w.w, acc[ce][3]);
        }
    }

    // ---- bias + tanh ----
    float h[4][4];
    #pragma unroll
    for (int ce = 0; ce < 4; ++ce)
        #pragma unroll
        for (int cf = 0; cf < 4; ++cf)
            h[ce][cf] = fast_tanh(acc[ce][cf] + b1s[f0 + cf]);

    __syncthreads();  // all Es + W1s reads done

    // Ht (transposed) into Es; W2 into W1s buffer
    #pragma unroll
    for (int cf = 0; cf < 4; ++cf) {
        #pragma unroll
        for (int j = 0; j < 4; ++j) {
            int ce = (j + g) & 3;          // rotation: 2-way banks, free
            Es[(f0 + cf) * ESTRIDE + e0 + ce] = h[ce][cf];
        }
    }
    #pragma unroll
    for (int i = 0; i < 16; ++i) W1s[t + 256 * i] = w2r[i];
    __syncthreads();

    // ---- GEMM2: h2[e][f] = b2[f] + sum_k Ht[k][e] * W2[k][f] ----
    float acc2[4][4] = {{0.f,0.f,0.f,0.f},{0.f,0.f,0.f,0.f},
                        {0.f,0.f,0.f,0.f},{0.f,0.f,0.f,0.f}};
    #pragma unroll 8
    for (int k = 0; k < HID; ++k) {
        float4 w = *(const float4*)&W1s[k * HID + f0];
        float ev[4];
        #pragma unroll
        for (int c = 0; c < 4; ++c) ev[c] = Es[k * ESTRIDE + e0 + c];
        #pragma unroll
        for (int ce = 0; ce < 4; ++ce) {
            acc2[ce][0] = fmaf(ev[ce], w.x, acc2[ce][0]);
            acc2[ce][1] = fmaf(ev[ce], w.y, acc2[ce][1]);
            acc2[ce][2] = fmaf(ev[ce], w.z, acc2[ce][2]);
            acc2[ce][3] = fmaf(ev[ce], w.w, acc2[ce][3]);
        }
    }
    __syncthreads();                      // Es reads done; repurpose

    // ---- zero segment accumulator (reuse Es) + denacc ----
    for (int i = t; i < HID * ESTRIDE; i += 256) Es[i] = 0.f;
    if (t < TE) denacc[t] = 0.f;

    // ---- gather atom[src], msg, attention ----
    float4 cf4 = *(const float4*)&cfs[f0];
    float msg[4][4];
    float partial[4];
    #pragma unroll
    for (int ce = 0; ce < 4; ++ce) {
        int s = srcs[e0 + ce];
        float4 a = *(const float4*)&atom[(size_t)s * HID + f0];
        float h2x = acc2[ce][0] + b2s[f0 + 0];
        float h2y = acc2[ce][1] + b2s[f0 + 1];
        float h2z = acc2[ce][2] + b2s[f0 + 2];
        float h2w = acc2[ce][3] + b2s[f0 + 3];
        msg[ce][0] = a.x * h2x;
        msg[ce][1] = a.y * h2y;
        msg[ce][2] = a.z * h2z;
        msg[ce][3] = a.w * h2w;
        partial[ce] = msg[ce][0]*cf4.x + msg[ce][1]*cf4.y
                    + msg[ce][2]*cf4.z + msg[ce][3]*cf4.w;
    }
    #pragma unroll
    for (int m = 1; m < 16; m <<= 1) {
        #pragma unroll
        for (int ce = 0; ce < 4; ++ce)
            partial[ce] += __shfl_xor(partial[ce], m);
    }
    float at[4];
    #pragma unroll
    for (int ce = 0; ce < 4; ++ce)
        at[ce] = (eb + e0 + ce < E) ? __expf(partial[ce]) : 0.f;

    __syncthreads();                      // zeroing complete

    // ---- register run-combine, LDS-atomic into segment accumulator ----
    {
        int curseg = seg[e0];
        float r0 = msg[0][0]*at[0], r1 = msg[0][1]*at[0];
        float r2 = msg[0][2]*at[0], r3 = msg[0][3]*at[0];
        float rd = at[0];
        #pragma unroll
        for (int ce = 1; ce < 4; ++ce) {
            int s2 = seg[e0 + ce];
            if (s2 == curseg) {
                r0 = fmaf(msg[ce][0], at[ce], r0);
                r1 = fmaf(msg[ce][1], at[ce], r1);
                r2 = fmaf(msg[ce][2], at[ce], r2);
                r3 = fmaf(msg[ce][3], at[ce], r3);
                rd += at[ce];
            } else {
                float* p = &Es[curseg * ESTRIDE + f0];
                atomicAdd(p + 0, r0); atomicAdd(p + 1, r1);
                atomicAdd(p + 2, r2); atomicAdd(p + 3, r3);
                if ((t & 15) == 0) atomicAdd(&denacc[curseg], rd);
                curseg = s2;
                r0 = msg[ce][0]*at[ce]; r1 = msg[ce][1]*at[ce];
                r2 = msg[ce][2]*at[ce]; r3 = msg[ce][3]*at[ce];
                rd = at[ce];
            }
        }
        float* p = &Es[curseg * ESTRIDE + f0];
        atomicAdd(p + 0, r0); atomicAdd(p + 1, r1);
        atomicAdd(p + 2, r2); atomicAdd(p + 3, r3);
        if ((t & 15) == 0) atomicAdd(&denacc[curseg], rd);
    }
    __syncthreads();

    // ---- flush: interior segments = plain stores, boundary = atomics ----
    {
        int nseg = nseg_s;
        int s = t >> 2;
        int q = t & 3;
        if (s < nseg) {
            int d = segdest[s];
            bool bnd = (s == 0 && d == prevd_s) ||
                       (s == nseg - 1 && d == nextd_s);
            float* np = num + (size_t)d * HID + q * 16;
            const float* sp = &Es[s * ESTRIDE + q * 16];
            if (bnd) {
                #pragma unroll
                for (int j = 0; j < 16; ++j) atomicAdd(np + j, sp[j]);
                if (q == 0) atomicAdd(&den[d], denacc[s]);
            } else {
                #pragma unroll
                for (int j = 0; j < 4; ++j)
                    ((float4*)np)[j] = *(const float4*)(sp + 4 * j);
                if (q == 0) den[d] = denacc[s];
            }
        }
    }
}

__global__ __launch_bounds__(256) void finalize_kernel(
    float* __restrict__ out, const float* __restrict__ den, int n16)
{
    int i = blockIdx.x * blockDim.x + threadIdx.x;
    if (i >= n16) return;
    float d = den[i >> 4];
    if (d > 0.f) {
        float4* p = (float4*)out + i;
        float4 v = *p;
        float r = 1.0f / d;
        v.x *= r; v.y *= r; v.z *= r; v.w *= r;
        *p = v;
    }
}

extern "C" void kernel_launch(void* const* d_in, const int* in_sizes, int n_in,
                              void* d_out, int out_size, void* d_ws, size_t ws_size,
                              hipStream_t stream) {
    const float* atom      = (const float*)d_in[0];
    const float* edge_emb  = (const float*)d_in[1];
    const float* W1        = (const float*)d_in[2];
    const float* b1        = (const float*)d_in[3];
    const float* W2        = (const float*)d_in[4];
    const float* b2        = (const float*)d_in[5];
    const float* coef      = (const float*)d_in[6];
    const int*   edge_list = (const int*)d_in[7];   // int32

    const int N = in_sizes[0] / HID;   // 50000
    const int E = in_sizes[1] / HID;   // 800000

    // ws layout: [den: N floats][cursor: N ints][blocksums: 64 ints][perm: E ints]
    float* den       = (float*)d_ws;
    int*   cursor    = (int*)d_ws + N;
    int*   blocksums = (int*)d_ws + 2 * N;
    int*   perm      = (int*)d_ws + 2 * N + 64;

    hipMemsetAsync(d_out, 0, (size_t)N * HID * sizeof(float), stream);
    hipMemsetAsync(d_ws, 0, (size_t)(2 * N) * sizeof(int), stream);  // den+cursor

    int eblk = (E + 255) / 256;
    int nb   = (N + 1023) / 1024;      // 49 (must be <= 64 for scanB)
    hist_kernel<<<eblk, 256, 0, stream>>>((const int2*)edge_list, cursor, E);
    scanA_kernel<<<nb, 1024, 0, stream>>>(cursor, blocksums, N);
    scanB_kernel<<<1, 64, 0, stream>>>(blocksums, nb);
    scanC_kernel<<<nb, 1024, 0, stream>>>(cursor, blocksums, N);
    perm_kernel<<<eblk, 256, 0, stream>>>((const int2*)edge_list, cursor, perm, E);

    int nblk = (E + TE - 1) / TE;      // 12500
    edge_mlp_sorted<<<nblk, 256, 0, stream>>>(
        atom, edge_emb, W1, b1, W2, b2, coef, edge_list, perm,
        (float*)d_out, den, E);

    int n16 = N * (HID / 4);
    finalize_kernel<<<(n16 + 255) / 256, 256, 0, stream>>>((float*)d_out, den, n16);
}

// Round 5
// 557.148 us; speedup vs baseline: 1.7630x; 1.1181x over previous
//
#include <hip/hip_runtime.h>
#include <math.h>

// ContinuousFilterConv, round 5: R4 (split-bf16 MFMA MLP) + race fix.
// R4 post-mortem: NaN came from a cross-wave LDS race -- H1 aliases A1 and
// wave w's h1 slice overlaps OTHER waves' A-fragments; h1 was written with
// no barrier after GEMM1's A-frag register preloads. Fix: __syncthreads()
// between GEMM1 and the h1 writeback (also guards ACC's reuse of B1).

#define TE 64
#define HID 64

typedef __attribute__((ext_vector_type(8))) short short8;
typedef __attribute__((ext_vector_type(4))) float float4v;

__device__ __forceinline__ float fast_tanh(float x) {
    float t = __expf(2.0f * x);
    return 1.0f - 2.0f * __builtin_amdgcn_rcpf(t + 1.0f);
}

__device__ __forceinline__ void split_bf16(float x, unsigned short& hi,
                                           unsigned short& lo) {
    unsigned b = __float_as_uint(x);
    hi = (unsigned short)(b >> 16);
    float hf = __uint_as_float(b & 0xffff0000u);
    lo = (unsigned short)(__float_as_uint(x - hf) >> 16);
}

// ---------------- W pre-split into MFMA B-fragment order ----------------
// B frag for 16x16x32: lane(q,n) holds B[k=ks*32+q*8+j][f=nt*16+n], j=0..7.
// Linear: chunk = (nt*2+ks)*64 + q*16 + n, elem = chunk*8 + j.
// wpack: [W1h 4096][W1l 4096][W2h 4096][W2l 4096] u16.
__global__ __launch_bounds__(256) void pack_w(
    const float* __restrict__ W1, const float* __restrict__ W2,
    unsigned short* __restrict__ wpack)
{
    int t = threadIdx.x;
    for (int i = 0; i < 16; ++i) {
        int idx = t * 16 + i;              // 0..4095
        int k = idx >> 6, f = idx & 63;
        int nt = f >> 4, n = f & 15, ks = k >> 5, q = (k >> 3) & 3, j = k & 7;
        int fi = (((nt * 2 + ks) * 4 + q) * 16 + n) * 8 + j;
        unsigned short hi, lo;
        split_bf16(W1[idx], hi, lo);
        wpack[fi] = hi; wpack[4096 + fi] = lo;
        split_bf16(W2[idx], hi, lo);
        wpack[8192 + fi] = hi; wpack[12288 + fi] = lo;
    }
}

// ---------------- sort pipeline (unchanged from R3) ----------------

__global__ __launch_bounds__(256) void hist_kernel(
    const int2* __restrict__ edge_list, int* __restrict__ cursor, int E)
{
    int i = blockIdx.x * blockDim.x + threadIdx.x;
    if (i < E) atomicAdd(&cursor[edge_list[i].x], 1);
}

__global__ __launch_bounds__(1024) void scanA_kernel(
    int* __restrict__ a, int* __restrict__ blocksums, int N)
{
    __shared__ int wsum[16];
    const int t = threadIdx.x;
    const int lane = t & 63, wv = t >> 6;
    int i = blockIdx.x * 1024 + t;
    int x = (i < N) ? a[i] : 0;
    int v = x;
    #pragma unroll
    for (int d = 1; d < 64; d <<= 1) {
        int y = __shfl_up(v, d);
        if (lane >= d) v += y;
    }
    if (lane == 63) wsum[wv] = v;
    __syncthreads();
    if (wv == 0 && lane < 16) {
        int s = wsum[lane];
        #pragma unroll
        for (int d = 1; d < 16; d <<= 1) {
            int y = __shfl_up(s, d);
            if (lane >= d) s += y;
        }
        wsum[lane] = s;
    }
    __syncthreads();
    int incl = v + ((wv == 0) ? 0 : wsum[wv - 1]);
    if (i < N) a[i] = incl - x;
    if (t == 1023) blocksums[blockIdx.x] = incl;
}

__global__ __launch_bounds__(64) void scanB_kernel(int* __restrict__ bs, int nb)
{
    int lane = threadIdx.x;
    int x = (lane < nb) ? bs[lane] : 0;
    int v = x;
    #pragma unroll
    for (int d = 1; d < 64; d <<= 1) {
        int y = __shfl_up(v, d);
        if (lane >= d) v += y;
    }
    if (lane < nb) bs[lane] = v - x;
}

__global__ __launch_bounds__(1024) void scanC_kernel(
    int* __restrict__ a, const int* __restrict__ blocksums, int N)
{
    int i = blockIdx.x * 1024 + threadIdx.x;
    if (i < N) a[i] += blocksums[blockIdx.x];
}

__global__ __launch_bounds__(256) void perm_kernel(
    const int2* __restrict__ edge_list, int* __restrict__ cursor,
    int* __restrict__ perm, int E)
{
    int i = blockIdx.x * blockDim.x + threadIdx.x;
    if (i < E) {
        int d = edge_list[i].x;
        int p = atomicAdd(&cursor[d], 1);
        perm[p] = i;
    }
}

// ---------------- fused MFMA MLP + segment-reduced scatter ----------------
// LDS map (SH, 48 KB):
//   [0,16K)  : B1 frags (W1 hi/lo)    -> later ACC (64x64 fp32)
//   [16,32K) : B2 frags (W2 hi/lo)
//   [32,48K) : A1 frags (edge hi/lo)  -> later h1 fp32 (4 KB per wave)
// NOTE: wave w's h1 slice overlaps OTHER waves' A1 frags -> the barrier
// between GEMM1 and the h1 write is load-bearing (R4's missing barrier).

__global__ __launch_bounds__(256, 3) void edge_mlp_sorted(
    const float* __restrict__ atom,
    const float* __restrict__ edge_emb,
    const unsigned short* __restrict__ wpack,
    const float* __restrict__ b1,
    const float* __restrict__ b2,
    const float* __restrict__ coef,
    const int*   __restrict__ edge_list,       // [E,2]: [dest, src]
    const int*   __restrict__ perm,
    float* __restrict__ num,
    float* __restrict__ den,
    int E)
{
    __shared__ __align__(16) unsigned char SH[49152];
    __shared__ float b1s[HID], b2s[HID], cfs[HID];
    __shared__ float denacc[TE];
    __shared__ int   srcs[TE], pidx[TE], seg[TE], segdest[TE];
    __shared__ int   nseg_s, prevd_s, nextd_s;

    unsigned short* B1 = (unsigned short*)SH;            // 8192 u16 (hi+lo)
    unsigned short* B2 = (unsigned short*)(SH + 16384);
    unsigned short* A1 = (unsigned short*)(SH + 32768);
    float* H1  = (float*)(SH + 32768);                   // aliases A1
    float* ACC = (float*)SH;                             // aliases B1

    const int t    = threadIdx.x;
    const int eb   = blockIdx.x * TE;
    const int w    = t >> 6;
    const int lane = t & 63;
    const int q    = lane >> 4;
    const int n    = lane & 15;

    // ---- phase 0: W frags global->LDS, biases, perm tile ----
    {
        const uint4* wp = (const uint4*)wpack;
        uint4* shw = (uint4*)SH;
        #pragma unroll
        for (int i = 0; i < 8; ++i)
            shw[t + 256 * i] = wp[t + 256 * i];   // 32 KB: B1 then B2
    }
    if (t < HID) { b1s[t] = b1[t]; b2s[t] = b2[t]; cfs[t] = coef[t]; }
    if (t < TE) {
        int eg = eb + t;
        if (eg >= E) eg = E - 1;
        pidx[t] = perm[eg];
    } else if (t == 64) {
        int pd = -1, nd = -1;
        if (eb > 0)      pd = edge_list[2 * perm[eb - 1]];
        if (eb + TE < E) nd = edge_list[2 * perm[eb + TE]];
        prevd_s = pd; nextd_s = nd;
    }
    __syncthreads();

    // ---- phase 1: seg ids (wave 0) + edge tile -> A1 frags (hi/lo) ----
    if (t < TE) {
        int e = pidx[t];
        int d = edge_list[2 * e + 0];
        int s = edge_list[2 * e + 1];
        srcs[t] = s;
        int dprev = __shfl_up(d, 1);
        int head = (t == 0 || dprev != d) ? 1 : 0;
        int sv = head;
        #pragma unroll
        for (int m = 1; m < 64; m <<= 1) {
            int y = __shfl_up(sv, m);
            if (t >= m) sv += y;
        }
        int sidx = sv - 1;
        seg[t] = sidx;
        if (head) segdest[sidx] = d;
        if (t == 63) nseg_s = sv;
    }
    {
        // thread t: edge e=t>>2 (wave-local staging), k-chunk c=t&3
        const int e = t >> 2, c = t & 3;
        const float* sp = edge_emb + (size_t)pidx[e] * HID + c * 16;
        float x[16];
        #pragma unroll
        for (int i = 0; i < 4; ++i) {
            float4 v = ((const float4*)sp)[i];
            x[4*i] = v.x; x[4*i+1] = v.y; x[4*i+2] = v.z; x[4*i+3] = v.w;
        }
        int wA = e >> 4, m = e & 15, ks = c >> 1;
        int cA = wA * 128 + ks * 64 + ((2 * c) & 3) * 16 + m;
        int cB = wA * 128 + ks * 64 + (((2 * c) & 3) + 1) * 16 + m;
        short8 hA, lA, hB, lB;
        #pragma unroll
        for (int j = 0; j < 8; ++j) {
            unsigned short hi, lo;
            split_bf16(x[j], hi, lo);
            hA[j] = (short)hi; lA[j] = (short)lo;
            split_bf16(x[8 + j], hi, lo);
            hB[j] = (short)hi; lB[j] = (short)lo;
        }
        *(short8*)&A1[cA * 8]        = hA;
        *(short8*)&A1[4096 + cA * 8] = lA;
        *(short8*)&A1[cB * 8]        = hB;
        *(short8*)&A1[4096 + cB * 8] = lB;
    }
    __syncthreads();

    // ---- GEMM1: h1 = tanh(E @ W1 + b1), split-bf16 (AhBh+AhBl+AlBh) ----
    float4v c1[4];
    #pragma unroll
    for (int i = 0; i < 4; ++i) c1[i] = (float4v){0.f, 0.f, 0.f, 0.f};
    {
        short8 ah0 = *(const short8*)&A1[(w * 128 + lane) * 8];
        short8 ah1 = *(const short8*)&A1[(w * 128 + 64 + lane) * 8];
        short8 al0 = *(const short8*)&A1[4096 + (w * 128 + lane) * 8];
        short8 al1 = *(const short8*)&A1[4096 + (w * 128 + 64 + lane) * 8];
        #pragma unroll
        for (int nt = 0; nt < 4; ++nt) {
            #pragma unroll
            for (int ks = 0; ks < 2; ++ks) {
                int cb = (nt * 2 + ks) * 64 + lane;
                short8 bh = *(const short8*)&B1[cb * 8];
                short8 bl = *(const short8*)&B1[4096 + cb * 8];
                short8 ah = ks ? ah1 : ah0;
                short8 al = ks ? al1 : al0;
                c1[nt] = __builtin_amdgcn_mfma_f32_16x16x32_bf16(ah, bh, c1[nt], 0, 0, 0);
                c1[nt] = __builtin_amdgcn_mfma_f32_16x16x32_bf16(ah, bl, c1[nt], 0, 0, 0);
                c1[nt] = __builtin_amdgcn_mfma_f32_16x16x32_bf16(al, bh, c1[nt], 0, 0, 0);
            }
        }
    }

    // RACE FIX (R4 bug): wait for ALL waves to finish GEMM1 (their A1
    // register preloads + B1 reads) before overwriting A1 with h1 / B1 later.
    __syncthreads();

    // ---- tanh + write h1 fp32 (C-layout -> swizzled per-wave slice) ----
    // C/D: row m = q*4+reg (edge within wave), col = n; f = nt*16+n.
    {
        float* h1w = H1 + w * 1024;
        #pragma unroll
        for (int nt = 0; nt < 4; ++nt) {
            int f = nt * 16 + n;
            float bb = b1s[f];
            #pragma unroll
            for (int r = 0; r < 4; ++r) {
                int m = q * 4 + r;
                h1w[m * 64 + (f ^ ((m & 7) << 3))] = fast_tanh(c1[nt][r] + bb);
            }
        }
    }
    __syncthreads();   // h1 visible; B1 region now becomes ACC

    // ---- zero ACC (aliases B1) + denacc ----
    {
        float4* az = (float4*)ACC;
        #pragma unroll
        for (int i = 0; i < 4; ++i)
            az[t + 256 * i] = (float4){0.f, 0.f, 0.f, 0.f};
        if (t < TE) denacc[t] = 0.f;
    }

    // ---- read h1 back in A-operand arrangement, split to bf16 regs ----
    // A frag: lane holds h1[m=lane&15][k=ks2*32+q*8+j]
    short8 a2h[2], a2l[2];
    {
        const float* h1w = H1 + w * 1024;
        int m = lane & 15;
        #pragma unroll
        for (int ks2 = 0; ks2 < 2; ++ks2) {
            int F0 = (ks2 * 32 + q * 8) ^ ((m & 7) << 3);
            const float* sp = h1w + m * 64 + F0;
            float4 u0 = *(const float4*)&sp[0];
            float4 u1 = *(const float4*)&sp[4];
            float xv[8] = {u0.x, u0.y, u0.z, u0.w, u1.x, u1.y, u1.z, u1.w};
            #pragma unroll
            for (int j = 0; j < 8; ++j) {
                unsigned short hi, lo;
                split_bf16(xv[j], hi, lo);
                a2h[ks2][j] = (short)hi; a2l[ks2][j] = (short)lo;
            }
        }
    }

    // ---- GEMM2: h2 = h1 @ W2 + b2 ----
    float4v c2[4];
    #pragma unroll
    for (int i = 0; i < 4; ++i) c2[i] = (float4v){0.f, 0.f, 0.f, 0.f};
    #pragma unroll
    for (int nt = 0; nt < 4; ++nt) {
        #pragma unroll
        for (int ks = 0; ks < 2; ++ks) {
            int cb = (nt * 2 + ks) * 64 + lane;
            short8 bh = *(const short8*)&B2[cb * 8];
            short8 bl = *(const short8*)&B2[4096 + cb * 8];
            c2[nt] = __builtin_amdgcn_mfma_f32_16x16x32_bf16(a2h[ks], bh, c2[nt], 0, 0, 0);
            c2[nt] = __builtin_amdgcn_mfma_f32_16x16x32_bf16(a2h[ks], bl, c2[nt], 0, 0, 0);
            c2[nt] = __builtin_amdgcn_mfma_f32_16x16x32_bf16(a2l[ks], bh, c2[nt], 0, 0, 0);
        }
    }

    // ---- gather atom[src], msg, attention ----
    // Lane owns edges eL = w*16+q*4+r (r=0..3), features f = nt*16+n.
    float b2v[4], cfv[4];
    #pragma unroll
    for (int nt = 0; nt < 4; ++nt) {
        b2v[nt] = b2s[nt * 16 + n];
        cfv[nt] = cfs[nt * 16 + n];
    }
    float msg[4][4];   // [r][nt]
    float partial[4], at[4];
    #pragma unroll
    for (int r = 0; r < 4; ++r) {
        int s = srcs[w * 16 + q * 4 + r];
        const float* ap = atom + (size_t)s * HID + n;
        float p = 0.f;
        #pragma unroll
        for (int nt = 0; nt < 4; ++nt) {
            float hv = c2[nt][r] + b2v[nt];
            float av = ap[nt * 16];
            msg[r][nt] = av * hv;
            p = fmaf(msg[r][nt], cfv[nt], p);
        }
        partial[r] = p;
    }
    #pragma unroll
    for (int m = 1; m < 16; m <<= 1) {
        #pragma unroll
        for (int r = 0; r < 4; ++r)
            partial[r] += __shfl_xor(partial[r], m);
    }
    #pragma unroll
    for (int r = 0; r < 4; ++r) {
        int eg = eb + w * 16 + q * 4 + r;
        at[r] = (eg < E) ? __expf(partial[r]) : 0.f;
    }
    __syncthreads();   // ACC zeroing visible to all

    // ---- register run-combine over 4 consecutive sorted edges ----
    {
        int e0L = w * 16 + q * 4;
        int curseg = seg[e0L];
        float a0 = msg[0][0] * at[0], a1 = msg[0][1] * at[0];
        float a2 = msg[0][2] * at[0], a3 = msg[0][3] * at[0];
        float rd = at[0];
        #pragma unroll
        for (int r = 1; r < 4; ++r) {
            int s2 = seg[e0L + r];
            if (s2 == curseg) {
                a0 = fmaf(msg[r][0], at[r], a0);
                a1 = fmaf(msg[r][1], at[r], a1);
                a2 = fmaf(msg[r][2], at[r], a2);
                a3 = fmaf(msg[r][3], at[r], a3);
                rd += at[r];
            } else {
                float* p = &ACC[curseg * 64 + n];
                atomicAdd(p + 0,  a0); atomicAdd(p + 16, a1);
                atomicAdd(p + 32, a2); atomicAdd(p + 48, a3);
                if (n == 0) atomicAdd(&denacc[curseg], rd);
                curseg = s2;
                a0 = msg[r][0] * at[r]; a1 = msg[r][1] * at[r];
                a2 = msg[r][2] * at[r]; a3 = msg[r][3] * at[r];
                rd = at[r];
            }
        }
        float* p = &ACC[curseg * 64 + n];
        atomicAdd(p + 0,  a0); atomicAdd(p + 16, a1);
        atomicAdd(p + 32, a2); atomicAdd(p + 48, a3);
        if (n == 0) atomicAdd(&denacc[curseg], rd);
    }
    __syncthreads();

    // ---- flush: interior segments = stores, boundary = atomics ----
    {
        int nseg = nseg_s;
        int s = t >> 2;
        int qq = t & 3;
        if (s < nseg) {
            int d = segdest[s];
            bool bnd = (s == 0 && d == prevd_s) ||
                       (s == nseg - 1 && d == nextd_s);
            float* np = num + (size_t)d * HID + qq * 16;
            const float* sp = &ACC[s * 64 + qq * 16];
            if (bnd) {
                #pragma unroll
                for (int j = 0; j < 16; ++j) atomicAdd(np + j, sp[j]);
                if (qq == 0) atomicAdd(&den[d], denacc[s]);
            } else {
                #pragma unroll
                for (int j = 0; j < 4; ++j)
                    ((float4*)np)[j] = *(const float4*)(sp + 4 * j);
                if (qq == 0) den[d] = denacc[s];
            }
        }
    }
}

__global__ __launch_bounds__(256) void finalize_kernel(
    float* __restrict__ out, const float* __restrict__ den, int n16)
{
    int i = blockIdx.x * blockDim.x + threadIdx.x;
    if (i >= n16) return;
    float d = den[i >> 4];
    if (d > 0.f) {
        float4* p = (float4*)out + i;
        float4 v = *p;
        float r = 1.0f / d;
        v.x *= r; v.y *= r; v.z *= r; v.w *= r;
        *p = v;
    }
}

extern "C" void kernel_launch(void* const* d_in, const int* in_sizes, int n_in,
                              void* d_out, int out_size, void* d_ws, size_t ws_size,
                              hipStream_t stream) {
    const float* atom      = (const float*)d_in[0];
    const float* edge_emb  = (const float*)d_in[1];
    const float* W1        = (const float*)d_in[2];
    const float* b1        = (const float*)d_in[3];
    const float* W2        = (const float*)d_in[4];
    const float* b2        = (const float*)d_in[5];
    const float* coef      = (const float*)d_in[6];
    const int*   edge_list = (const int*)d_in[7];

    const int N = in_sizes[0] / HID;   // 50000
    const int E = in_sizes[1] / HID;   // 800000

    // ws: [den N f32][cursor N i32][blocksums 64][perm E i32][wpack 16384 u16]
    float* den       = (float*)d_ws;
    int*   cursor    = (int*)d_ws + N;
    int*   blocksums = (int*)d_ws + 2 * N;
    int*   perm      = (int*)d_ws + 2 * N + 64;
    unsigned short* wpack = (unsigned short*)((int*)d_ws + 2 * N + 64 + E);

    hipMemsetAsync(d_out, 0, (size_t)N * HID * sizeof(float), stream);
    hipMemsetAsync(d_ws, 0, (size_t)(2 * N) * sizeof(int), stream);

    pack_w<<<1, 256, 0, stream>>>(W1, W2, wpack);

    int eblk = (E + 255) / 256;
    int nb   = (N + 1023) / 1024;
    hist_kernel<<<eblk, 256, 0, stream>>>((const int2*)edge_list, cursor, E);
    scanA_kernel<<<nb, 1024, 0, stream>>>(cursor, blocksums, N);
    scanB_kernel<<<1, 64, 0, stream>>>(blocksums, nb);
    scanC_kernel<<<nb, 1024, 0, stream>>>(cursor, blocksums, N);
    perm_kernel<<<eblk, 256, 0, stream>>>((const int2*)edge_list, cursor, perm, E);

    int nblk = (E + TE - 1) / TE;
    edge_mlp_sorted<<<nblk, 256, 0, stream>>>(
        atom, edge_emb, wpack, b1, b2, coef, edge_list, perm,
        (float*)d_out, den, E);

    int n16 = N * (HID / 4);
    finalize_kernel<<<(n16 + 255) / 256, 256, 0, stream>>>((float*)d_out, den, n16);
}